// Round 17
// baseline (186.182 us; speedup 1.0000x reference)
//
#include <hip/hip_runtime.h>
#include <math.h>

#define Hh 128
#define Ww 128
#define HW (128*128)
#define CIN_OFF 196
#define COFF 432

typedef _Float16 half8 __attribute__((ext_vector_type(8)));
typedef _Float16 half4 __attribute__((ext_vector_type(4)));
typedef _Float16 half2v __attribute__((ext_vector_type(2)));
typedef float f32x4 __attribute__((ext_vector_type(4)));

static __device__ __forceinline__ half8 splat8(float v) {
  _Float16 h = (_Float16)v;
  half8 r = {h, h, h, h, h, h, h, h};
  return r;
}

// ---------------- kernel 0: ALL preprocessing in one launch -------------------------------
__global__ __launch_bounds__(256) void k_prep_all(
    const float* __restrict__ dcw, const float* __restrict__ w_off,
    const float* __restrict__ fp, const float* __restrict__ fn2,
    _Float16* __restrict__ wH, _Float16* __restrict__ BpT, _Float16* __restrict__ Bt,
    _Float16* __restrict__ featT) {
  const int bid = blockIdx.x;
  if (bid < 3375) {
    const int idx = bid * 256 + (int)threadIdx.x;
    if (idx < 73728) {            // wH[co][k*128+ci] = dcw[co][ci][k]
      const int co = idx / 1152;
      const int j  = idx - co * 1152;
      const int k  = j >> 7;
      const int ci = j & 127;
      wH[idx] = (_Float16)dcw[(co * 128 + ci) * 9 + k];
    } else if (idx < 73728 + 774144) {   // BpT[s][l4][n][8]
      const int j  = idx - 73728;
      const int c  = j & 7;
      const int n  = (j >> 3) % 448;
      const int sl = (j >> 3) / 448;
      const int l4 = sl & 3;
      const int s  = sl >> 2;
      const int t  = s / 6;
      const int cg = s - t * 6;
      const int ci = cg * 32 + l4 * 8 + c;
      BpT[j] = (_Float16)((n < COFF) ? w_off[((size_t)n * CIN_OFF + ci) * 9 + t] : 0.f);
    } else {                       // Bt[t][n][4] (tail ci 192..195)
      const int j = idx - 73728 - 774144;
      const int c = j & 3;
      const int n = (j >> 2) % 448;
      const int t = (j >> 2) / 448;
      Bt[j] = (_Float16)((n < COFF) ? w_off[((size_t)n * CIN_OFF + 192 + c) * 9 + t] : 0.f);
    }
  } else {
    const int t = (bid - 3375) * 256 + (int)threadIdx.x;  // 0..32767 = b*HW+hw
    const int b = t >> 14;
    const int hw = t & 16383;
#pragma unroll
    for (int g = 0; g < 16; ++g) {
      const float* src = (g < 8) ? fp : fn2;
      const int ch0 = (g & 7) * 8;
      half8 v;
#pragma unroll
      for (int c = 0; c < 8; ++c)
        v[c] = (_Float16)src[(size_t)(b * 64 + ch0 + c) * HW + hw];
      *(half8*)(featT + (((size_t)(b * 16 + g)) * HW + hw) * 8) = v;
    }
  }
}

// ---------------- kernel 1: offset conv, M-split (64 px/block), 2 blocks/CU ---------------
// grid (2 wt, 128 h, 2 b) = 512 blocks (2/CU). Block 512 thr (8 waves: 2M x 4N, M_wave=32).
// LDS/block: A[3][66][192] = 76KB + tail 1.6KB -> two blocks co-resident; block phases
// (staging / K-loop / epilogue) interleave across blocks, filling the 1-block/CU stalls
// that pinned rounds 8-16 at ~100us. K loop = round-15 barrier-free global-B form.
__global__ __launch_bounds__(512, 4) void k_offconv_mfma(
    const float* __restrict__ extra, const float* __restrict__ f1, const float* __restrict__ f2,
    const _Float16* __restrict__ BpT, const _Float16* __restrict__ Bt,
    const float* __restrict__ b_off,
    _Float16* __restrict__ off_pm, _Float16* __restrict__ mask_pm) {
  __shared__ __align__(16) _Float16 smA[3 * 66 * 192];  // 76,032 B (reused by epilogue)
  __shared__ __align__(16) _Float16 smT[3 * 66 * 4];    //  1,584 B
  const int wt   = blockIdx.x;
  const int h    = blockIdx.y;
  const int b    = blockIdx.z;
  const int w0   = wt * 64;
  const int tid  = (int)threadIdx.x;
  const int lane = tid & 63;
  const int wid  = tid >> 6;          // 0..7
  const int wm   = wid & 1;           // M-wave (co-SIMD pairs share A)
  const int wn   = (wid >> 1) & 3;    // N-wave
  const int m_base = wm * 32;
  const int n_base = wn * 112;
  const int l15 = lane & 15;
  const int l4  = lane >> 4;

  // ---- middle staging: px 1..64 (cols w0..w0+63): 3 r x 96 ci-pairs x 16 q = 4608 ----
#pragma unroll 3
  for (int it = 0; it < 9; ++it) {
    const int J   = tid + 512 * it;
    const int p2a = J & 15;
    const int qa  = (J >> 4) & 3;
    const int R   = J >> 6;                  // 0..71
    const int r   = R / 24;
    const int rem = R - 24 * r;              // 0..23
    const int qh  = rem & 3;
    const int p2h = rem >> 2;                // 0..5
    const int q   = qa + 4 * qh;             // 0..15
    const int p2  = p2a + 16 * p2h;          // 0..95
    const int ci  = 2 * p2;
    const int gh  = h - 1 + r;
    float4 va = {0.f, 0.f, 0.f, 0.f}, vb = va;
    if ((unsigned)gh < (unsigned)Hh) {
      const float* xp = extra + (size_t)(b * 192 + ci) * HW + gh * Ww + w0 + 4 * q;
      va = *(const float4*)xp;
      vb = *(const float4*)(xp + HW);
    }
    const float av[4] = {va.x, va.y, va.z, va.w};
    const float bv[4] = {vb.x, vb.y, vb.z, vb.w};
    const int biw = p2 >> 2;
#pragma unroll
    for (int i = 0; i < 4; ++i) {
      const int px = 1 + 4 * q + i;          // 1..64
      const int sw = ((biw & 24) | ((biw & 7) ^ (px & 7))) << 3;
      half2v pk; pk[0] = (_Float16)av[i]; pk[1] = (_Float16)bv[i];
      *(half2v*)(smA + (r * 66 + px) * 192 + sw + (ci & 7)) = pk;
    }
  }
  // ---- tail middle: ci 192..195 (f1, f2): 3 r x 2 pt x 16 q = 96 tasks ----
  if (tid < 96) {
    const int r   = tid >> 5;
    const int rem = tid & 31;
    const int pt  = rem >> 4;
    const int q   = rem & 15;
    const int gh  = h - 1 + r;
    float4 va = {0.f, 0.f, 0.f, 0.f}, vb = va;
    if ((unsigned)gh < (unsigned)Hh) {
      const float* xp = (pt ? f2 : f1) + (size_t)(b * 2) * HW + gh * Ww + w0 + 4 * q;
      va = *(const float4*)xp;
      vb = *(const float4*)(xp + HW);
    }
    const float av[4] = {va.x, va.y, va.z, va.w};
    const float bv[4] = {vb.x, vb.y, vb.z, vb.w};
#pragma unroll
    for (int i = 0; i < 4; ++i) {
      const int px = 1 + 4 * q + i;
      half2v pk; pk[0] = (_Float16)av[i]; pk[1] = (_Float16)bv[i];
      *(half2v*)(smT + (r * 66 + px) * 4 + 2 * pt) = pk;
    }
  }
  // ---- edge columns px=0 (col w0-1) and px=65 (col w0+64): load-or-zero ----
  // grid-stride over 588 tasks (round-14 lesson: never `if (tid < N>blockDim)`).
  for (int z = tid; z < 588; z += 512) {
    if (z < 576) {
      const int r    = z / 192;
      const int rem  = z - r * 192;
      const int side = rem / 96;
      const int p2   = rem - side * 96;
      const int px   = side ? 65 : 0;
      const int col  = w0 - 1 + px;          // w0-1 or w0+64
      const int ci   = 2 * p2;
      const int gh   = h - 1 + r;
      float s0 = 0.f, s1 = 0.f;
      if ((unsigned)gh < (unsigned)Hh && (unsigned)col < (unsigned)Ww) {
        const float* xp = extra + (size_t)(b * 192 + ci) * HW + gh * Ww + col;
        s0 = xp[0];
        s1 = xp[HW];
      }
      const int biw = p2 >> 2;
      const int sw = ((biw & 24) | ((biw & 7) ^ (px & 7))) << 3;
      half2v pk; pk[0] = (_Float16)s0; pk[1] = (_Float16)s1;
      *(half2v*)(smA + (r * 66 + px) * 192 + sw + (ci & 7)) = pk;
    } else {
      const int t2   = z - 576;              // 0..11
      const int r    = t2 >> 2;
      const int rem  = t2 & 3;
      const int side = rem >> 1;
      const int pt   = rem & 1;
      const int px   = side ? 65 : 0;
      const int col  = w0 - 1 + px;
      const int gh   = h - 1 + r;
      float s0 = 0.f, s1 = 0.f;
      if ((unsigned)gh < (unsigned)Hh && (unsigned)col < (unsigned)Ww) {
        const float* xp = (pt ? f2 : f1) + (size_t)(b * 2) * HW + gh * Ww + col;
        s0 = xp[0];
        s1 = xp[HW];
      }
      half2v pk; pk[0] = (_Float16)s0; pk[1] = (_Float16)s1;
      *(half2v*)(smT + (r * 66 + px) * 4 + 2 * pt) = pk;
    }
  }
  __syncthreads();

  // ---- barrier-free K loop: 9 taps x (6 x K32 + K16-tail), 14 MFMA per step/wave ----
  f32x4 acc[2][7];
#pragma unroll
  for (int i = 0; i < 2; ++i)
#pragma unroll
    for (int j = 0; j < 7; ++j) acc[i][j] = (f32x4){0.f, 0.f, 0.f, 0.f};

  const bool lz = (l4 == 0);
#pragma unroll 3
  for (int t = 0; t < 9; ++t) {
    const int ki = t / 3;
    const int kj = t - 3 * ki;
#pragma unroll
    for (int cg = 0; cg < 6; ++cg) {
      const int s4 = ((t * 6 + cg) * 4 + l4) * 448;
      half8 bf[7];
#pragma unroll
      for (int f = 0; f < 7; ++f)
        bf[f] = *(const half8*)(BpT + (size_t)(s4 + n_base + f * 16 + l15) * 8);
      half8 af[2];
#pragma unroll
      for (int mf = 0; mf < 2; ++mf) {
        const int px = m_base + mf * 16 + l15 + kj;   // 0..65
        const int bi = cg * 4 + l4;
        af[mf] = *(const half8*)(smA + (ki * 66 + px) * 192 +
                                 (((bi & 24) | ((bi & 7) ^ (px & 7))) << 3));
      }
#pragma unroll
      for (int mf = 0; mf < 2; ++mf)
#pragma unroll
        for (int f = 0; f < 7; ++f)
          acc[mf][f] = __builtin_amdgcn_mfma_f32_16x16x32_f16(af[mf], bf[f], acc[mf][f], 0, 0, 0);
    }
    // tail: ci 192..195 as a l4==0-masked K32 MFMA
    half8 aft[2];
#pragma unroll
    for (int mf = 0; mf < 2; ++mf) {
      const int px = m_base + mf * 16 + l15 + kj;
      const half4 tv = *(const half4*)(smT + (ki * 66 + px) * 4);
      half8 a = {0, 0, 0, 0, 0, 0, 0, 0};
      if (lz) { a[0] = tv[0]; a[1] = tv[1]; a[2] = tv[2]; a[3] = tv[3]; }
      aft[mf] = a;
    }
#pragma unroll
    for (int f = 0; f < 7; ++f) {
      const half4 wv = *(const half4*)(Bt + (size_t)(t * 448 + n_base + f * 16 + l15) * 4);
      half8 bb = {0, 0, 0, 0, 0, 0, 0, 0};
      if (lz) { bb[0] = wv[0]; bb[1] = wv[1]; bb[2] = wv[2]; bb[3] = wv[3]; }
#pragma unroll
      for (int mf = 0; mf < 2; ++mf)
        acc[mf][f] = __builtin_amdgcn_mfma_f32_16x16x32_f16(aft[mf], bb, acc[mf][f], 0, 0, 0);
    }
  }

  // ---- epilogue: activation+flow -> LDS so[64][456] fp16 -> coalesced stores ----
  __syncthreads();
  _Float16* so = smA;
  const int hw0 = h * Ww + w0;
#pragma unroll
  for (int f = 0; f < 7; ++f) {
    const int n = n_base + f * 16 + l15;
    const float bias = (n < COFF) ? b_off[n] : 0.f;
    const bool isOff = (n < 288);
    const float* fl = (n < 144) ? f1 : f2;
    const size_t fladd = (size_t)(b * 2 + ((n & 1) ^ 1)) * HW + hw0;
#pragma unroll
    for (int mf = 0; mf < 2; ++mf) {
#pragma unroll
      for (int rr = 0; rr < 4; ++rr) {
        const int px = m_base + mf * 16 + l4 * 4 + rr;   // 0..63
        const float v = acc[mf][f][rr] + bias;
        float val;
        if (isOff) {
          const float e = __expf(2.f * v);
          val = 10.f * (1.f - 2.f / (e + 1.f)) + fl[fladd + px];
        } else {
          val = 1.f / (1.f + __expf(-v));
        }
        so[px * 456 + n] = (_Float16)val;
      }
    }
  }
  __syncthreads();
  for (int T = tid; T < 2304; T += 512) {   // off: 64 px x 36 chunks
    const int px = T / 36, c = T - px * 36;
    const half8 v = *(const half8*)(so + px * 456 + c * 8);
    *(half8*)(off_pm + ((size_t)b * HW + hw0 + px) * 288 + c * 8) = v;
  }
  for (int T = tid; T < 1152; T += 512) {   // mask: 64 px x 18 chunks
    const int px = T / 18, c = T - px * 18;
    const half8 v = *(const half8*)(so + px * 456 + 288 + c * 8);
    *(half8*)(mask_pm + ((size_t)b * HW + hw0 + px) * 144 + c * 8) = v;
  }
}

// ---------------- kernel 2: modulated deformable conv (unchanged) -------------------------
__global__ __launch_bounds__(256, 4) void k_deform2(
    const _Float16* __restrict__ featT, const _Float16* __restrict__ off_pm,
    const _Float16* __restrict__ mask_pm, const _Float16* __restrict__ wH,
    const float* __restrict__ dcb, float* __restrict__ out) {
  __shared__ __align__(16) char smem[16 * 1160 * 2];
  _Float16* sm = (_Float16*)smem;
  float* red = (float*)smem;
  const int w0  = blockIdx.x * 16;
  const int h   = blockIdx.y;
  const int b   = blockIdx.z;
  const int tid = (int)threadIdx.x;
  const int lane = tid & 63, wid = tid >> 6;
  const int l15 = lane & 15, l4 = lane >> 4;

  half2v offv[9];
  _Float16 mkv[9];
#pragma unroll
  for (int i = 0; i < 9; ++i) {
    const int p   = tid + i * 256;
    const int pix = p / 144;
    const int r   = p - pix * 144;
    const int w   = w0 + pix;
    const int hw  = h * Ww + w;
    offv[i] = *(const half2v*)(off_pm + ((size_t)b * HW + hw) * 288 + 2 * r);
    mkv[i]  = mask_pm[((size_t)b * HW + hw) * 144 + r];
  }
#pragma unroll
  for (int i = 0; i < 9; ++i) {
    const int p   = tid + i * 256;
    const int pix = p / 144;
    const int r   = p - pix * 144;
    const int g   = r / 9;
    const int k   = r - g * 9;
    const int w   = w0 + pix;
    const float mk = (float)mkv[i];
    const int ki = (k >= 6) ? 2 : (k >= 3 ? 1 : 0);
    const int kj = k - 3 * ki;
    const float py = (float)(h - 1 + ki) + (float)offv[i][0];
    const float px = (float)(w - 1 + kj) + (float)offv[i][1];
    const float y0f = floorf(py), x0f = floorf(px);
    const int y0 = (int)y0f, x0 = (int)x0f;
    const float ly = py - y0f, lx = px - x0f;
    const float hy = 1.f - ly, hx = 1.f - lx;
    const int y1 = y0 + 1, x1 = x0 + 1;
    const bool vy0 = (unsigned)y0 < (unsigned)Hh, vy1 = (unsigned)y1 < (unsigned)Hh;
    const bool vx0 = (unsigned)x0 < (unsigned)Ww, vx1 = (unsigned)x1 < (unsigned)Ww;
    const float w00 = (vy0 && vx0) ? hy * hx : 0.f;
    const float w01 = (vy0 && vx1) ? hy * lx : 0.f;
    const float w10 = (vy1 && vx0) ? ly * hx : 0.f;
    const float w11 = (vy1 && vx1) ? ly * lx : 0.f;
    const int cy0 = min(max(y0, 0), Hh - 1), cy1 = min(max(y1, 0), Hh - 1);
    const int cx0 = min(max(x0, 0), Ww - 1), cx1 = min(max(x1, 0), Ww - 1);
    const _Float16* gbase = featT + ((size_t)(b * 16 + g) * HW) * 8;
    const half8 s00 = *(const half8*)(gbase + (cy0 * Ww + cx0) * 8);
    const half8 s01 = *(const half8*)(gbase + (cy0 * Ww + cx1) * 8);
    const half8 s10 = *(const half8*)(gbase + (cy1 * Ww + cx0) * 8);
    const half8 s11 = *(const half8*)(gbase + (cy1 * Ww + cx1) * 8);
    half8 v = s00 * splat8(w00) + s01 * splat8(w01) + s10 * splat8(w10) + s11 * splat8(w11);
    v = v * splat8(mk);
    const int swz = (g ^ (k & 7)) << 3;
    *(half8*)(sm + pix * 1160 + k * 128 + swz) = v;
  }
  __syncthreads();

  f32x4 acc[4];
#pragma unroll
  for (int nf = 0; nf < 4; ++nf) acc[nf] = (f32x4){0.f, 0.f, 0.f, 0.f};
#pragma unroll
  for (int j = 0; j < 9; ++j) {
    const int s  = wid * 9 + j;
    const int k  = s >> 2;
    const int cg = s & 3;
    const int gidx = cg * 4 + l4;
    const half8 af = *(const half8*)(sm + l15 * 1160 + k * 128 + ((gidx ^ (k & 7)) << 3));
    const int koff = s * 32 + l4 * 8;
#pragma unroll
    for (int nf = 0; nf < 4; ++nf) {
      const half8 bf = *(const half8*)(wH + (nf * 16 + l15) * 1152 + koff);
      acc[nf] = __builtin_amdgcn_mfma_f32_16x16x32_f16(af, bf, acc[nf], 0, 0, 0);
    }
  }
  __syncthreads();
#pragma unroll
  for (int nf = 0; nf < 4; ++nf)
#pragma unroll
    for (int rr = 0; rr < 4; ++rr)
      red[(wid * 16 + l4 * 4 + rr) * 66 + nf * 16 + l15] = acc[nf][rr];
  __syncthreads();

  const int m  = tid & 15;
  const int ng = tid >> 4;
#pragma unroll
  for (int i = 0; i < 4; ++i) {
    const int n = ng + 16 * i;
    float val = red[(0 * 16 + m) * 66 + n] + red[(1 * 16 + m) * 66 + n] +
                red[(2 * 16 + m) * 66 + n] + red[(3 * 16 + m) * 66 + n];
    out[(size_t)(b * 64 + n) * HW + h * Ww + w0 + m] = val + dcb[n];
  }
}

extern "C" void kernel_launch(void* const* d_in, const int* in_sizes, int n_in,
                              void* d_out, int out_size, void* d_ws, size_t ws_size,
                              hipStream_t stream) {
  const float* extra = (const float*)d_in[0];
  const float* f1    = (const float*)d_in[1];
  const float* f2    = (const float*)d_in[2];
  const float* fp    = (const float*)d_in[3];
  const float* fn2   = (const float*)d_in[4];
  const float* w_off = (const float*)d_in[5];
  const float* b_off = (const float*)d_in[6];
  const float* dcw   = (const float*)d_in[7];
  const float* dcb   = (const float*)d_in[8];
  float* out = (float*)d_out;

  // ws layout (~40 MB)
  _Float16* off_pm  = (_Float16*)d_ws;                   // 2*HW*288 fp16
  _Float16* mask_pm = off_pm + (size_t)2 * 288 * HW;     // 2*HW*144 fp16
  _Float16* featT   = mask_pm + (size_t)2 * 144 * HW;    // 2*16*HW*8 fp16
  _Float16* BpT     = featT + (size_t)2 * 128 * HW;      // 774144 fp16
  _Float16* Bt      = BpT + 774144;                      // 16128 fp16
  _Float16* wH      = Bt + 16128;                        // 73728 fp16

  hipLaunchKernelGGL(k_prep_all, dim3(3503), dim3(256), 0, stream,
                     dcw, w_off, fp, fn2, wH, BpT, Bt, featT);
  hipLaunchKernelGGL(k_offconv_mfma, dim3(2, 128, 2), dim3(512), 0, stream,
                     extra, f1, f2, BpT, Bt, b_off, off_pm, mask_pm);
  hipLaunchKernelGGL(k_deform2, dim3(8, 128, 2), dim3(256), 0, stream,
                     featT, off_pm, mask_pm, wH, dcb, out);
}

// Round 18
// 176.683 us; speedup vs baseline: 1.0538x; 1.0538x over previous
//
#include <hip/hip_runtime.h>
#include <math.h>

#define Hh 128
#define Ww 128
#define HW (128*128)
#define CIN_OFF 196
#define COFF 432

typedef _Float16 half8 __attribute__((ext_vector_type(8)));
typedef _Float16 half4 __attribute__((ext_vector_type(4)));
typedef _Float16 half2v __attribute__((ext_vector_type(2)));
typedef float f32x4 __attribute__((ext_vector_type(4)));

static __device__ __forceinline__ half8 splat8(float v) {
  _Float16 h = (_Float16)v;
  half8 r = {h, h, h, h, h, h, h, h};
  return r;
}

// ---------------- kernel 0: ALL preprocessing in one launch -------------------------------
// blocks [0,288): wH | [288,624): BpT (thread-per-(n,ci), coalesced reads) |
// [624,687): Bt | [687,815): featT
__global__ __launch_bounds__(256) void k_prep_all(
    const float* __restrict__ dcw, const float* __restrict__ w_off,
    const float* __restrict__ fp, const float* __restrict__ fn2,
    _Float16* __restrict__ wH, _Float16* __restrict__ BpT, _Float16* __restrict__ Bt,
    _Float16* __restrict__ featT) {
  const int bid = blockIdx.x;
  if (bid < 288) {                     // wH[co][k*128+ci] = dcw[co][ci][k]
    const int idx = bid * 256 + (int)threadIdx.x;
    const int co = idx / 1152;
    const int j  = idx - co * 1152;
    const int k  = j >> 7;
    const int ci = j & 127;
    wH[idx] = (_Float16)dcw[(co * 128 + ci) * 9 + k];
  } else if (bid < 624) {              // BpT[s][l4][n][8]; thread per (n, ci<192)
    const int idx = (bid - 288) * 256 + (int)threadIdx.x;   // 0..86015
    const int n  = idx / 192;          // 0..447
    const int ci = idx - n * 192;      // 0..191
    const int l4 = (ci >> 3) & 3;
    const int c  = ci & 7;
    const int cg = ci >> 5;
    const float* src = w_off + ((size_t)n * CIN_OFF + ci) * 9;
#pragma unroll
    for (int t = 0; t < 9; ++t) {
      const float v = (n < COFF) ? src[t] : 0.f;
      BpT[((size_t)((t * 6 + cg) * 4 + l4) * 448 + n) * 8 + c] = (_Float16)v;
    }
  } else if (bid < 687) {              // Bt[t][n][4] (tail ci 192..195)
    const int j = (bid - 624) * 256 + (int)threadIdx.x;
    if (j < 16128) {
      const int c = j & 3;
      const int n = (j >> 2) % 448;
      const int t = (j >> 2) / 448;
      Bt[j] = (_Float16)((n < COFF) ? w_off[((size_t)n * CIN_OFF + 192 + c) * 9 + t] : 0.f);
    }
  } else {                             // featT[b][g][hw][8c]
    const int t = (bid - 687) * 256 + (int)threadIdx.x;  // 0..32767 = b*HW+hw
    const int b = t >> 14;
    const int hw = t & 16383;
#pragma unroll
    for (int g = 0; g < 16; ++g) {
      const float* src = (g < 8) ? fp : fn2;
      const int ch0 = (g & 7) * 8;
      half8 v;
#pragma unroll
      for (int c = 0; c < 8; ++c)
        v[c] = (_Float16)src[(size_t)(b * 64 + ch0 + c) * HW + hw];
      *(half8*)(featT + (((size_t)(b * 16 + g)) * HW + hw) * 8) = v;
    }
  }
}

// ---------------- kernel 1: offset conv (round-15 best: 99.5us) ---------------------------
// grid (128 h, 2 b), block 512 (8 waves: 2M x 4N, M_wave=64). Full-K LDS, barrier-free.
__global__ __launch_bounds__(512, 2) void k_offconv_mfma(
    const float* __restrict__ extra, const float* __restrict__ f1, const float* __restrict__ f2,
    const _Float16* __restrict__ BpT, const _Float16* __restrict__ Bt,
    const float* __restrict__ b_off,
    _Float16* __restrict__ off_pm, _Float16* __restrict__ mask_pm) {
  __shared__ __align__(16) _Float16 smA[3 * 130 * 192];  // 149,760 B (reused by epilogue)
  __shared__ __align__(16) _Float16 smT[3 * 130 * 4];    //   3,120 B
  const int h    = blockIdx.x;
  const int b    = blockIdx.y;
  const int tid  = (int)threadIdx.x;
  const int lane = tid & 63;
  const int wid  = tid >> 6;          // 0..7
  const int wm   = wid & 1;
  const int wn   = (wid >> 1) & 3;
  const int m_base = wm * 64;
  const int n_base = wn * 112;
  const int l15 = lane & 15;
  const int l4  = lane >> 4;

  // ---- zero px=0 / px=129 edge columns (grid-stride: 588 tasks, any block size) ----
  for (int z = tid; z < 588; z += 512) {
    const int p2 = z % 98;
    const int rr = z / 98;
    const int r  = (rr >= 3) ? (rr - 3) : rr;
    const int px = (rr >= 3) ? 129 : 0;
    if (p2 < 96) {
      const int ci = 2 * p2, biw = ci >> 3;
      const int sw = ((biw & 24) | ((biw & 7) ^ (px & 7))) << 3;
      *(half2v*)(smA + (r * 130 + px) * 192 + sw + (ci & 7)) = (half2v){(_Float16)0.f, (_Float16)0.f};
    } else {
      *(half2v*)(smT + (r * 130 + px) * 4 + 2 * (p2 - 96)) = (half2v){(_Float16)0.f, (_Float16)0.f};
    }
  }

  // ---- main staging: 3 r x 96 ci-pairs x 32 q = 9216 tasks = 18 x 512 ----
#pragma unroll 3
  for (int j = 0; j < 18; ++j) {
    const int J   = tid + 512 * j;
    const int p2a = J & 15;
    const int qa  = (J >> 4) & 3;
    const int R   = J >> 6;                  // 0..143
    const int r   = R / 48;
    const int rem = R - 48 * r;
    const int qh  = rem & 7;
    const int p2h = rem >> 3;                // 0..5
    const int q   = qa + 4 * qh;             // 0..31
    const int p2  = p2a + 16 * p2h;          // 0..95
    const int ci  = 2 * p2;
    const int gh  = h - 1 + r;
    float4 va = {0.f, 0.f, 0.f, 0.f}, vb = va;
    if ((unsigned)gh < (unsigned)Hh) {
      const float* xp = extra + (size_t)(b * 192 + ci) * HW + gh * Ww + 4 * q;
      va = *(const float4*)xp;
      vb = *(const float4*)(xp + HW);
    }
    const float av[4] = {va.x, va.y, va.z, va.w};
    const float bv[4] = {vb.x, vb.y, vb.z, vb.w};
    const int biw = p2 >> 2;
#pragma unroll
    for (int i = 0; i < 4; ++i) {
      const int px = 1 + 4 * q + i;
      const int sw = ((biw & 24) | ((biw & 7) ^ (px & 7))) << 3;
      half2v pk; pk[0] = (_Float16)av[i]; pk[1] = (_Float16)bv[i];
      *(half2v*)(smA + (r * 130 + px) * 192 + sw + (ci & 7)) = pk;
    }
  }
  // ---- tail staging: ci 192..195 (f1, f2) ----
  if (tid < 192) {
    const int q   = tid & 31;
    const int p2t = (tid >> 5) & 1;
    const int r   = tid >> 6;
    const int gh  = h - 1 + r;
    float4 va = {0.f, 0.f, 0.f, 0.f}, vb = va;
    if ((unsigned)gh < (unsigned)Hh) {
      const float* xp = (p2t ? f2 : f1) + (size_t)(b * 2) * HW + gh * Ww + 4 * q;
      va = *(const float4*)xp;
      vb = *(const float4*)(xp + HW);
    }
    const float av[4] = {va.x, va.y, va.z, va.w};
    const float bv[4] = {vb.x, vb.y, vb.z, vb.w};
#pragma unroll
    for (int i = 0; i < 4; ++i) {
      const int px = 1 + 4 * q + i;
      half2v pk; pk[0] = (_Float16)av[i]; pk[1] = (_Float16)bv[i];
      *(half2v*)(smT + (r * 130 + px) * 4 + 2 * p2t) = pk;
    }
  }
  __syncthreads();

  // ---- barrier-free K loop: 9 taps x (6 x K32 + K16-tail), 28 MFMA per step ----
  f32x4 acc[4][7];
#pragma unroll
  for (int i = 0; i < 4; ++i)
#pragma unroll
    for (int j = 0; j < 7; ++j) acc[i][j] = (f32x4){0.f, 0.f, 0.f, 0.f};

  const bool lz = (l4 == 0);
#pragma unroll 3
  for (int t = 0; t < 9; ++t) {
    const int ki = t / 3;
    const int kj = t - 3 * ki;
#pragma unroll
    for (int cg = 0; cg < 6; ++cg) {
      const int s4 = ((t * 6 + cg) * 4 + l4) * 448;
      half8 bf[7];
#pragma unroll
      for (int f = 0; f < 7; ++f)
        bf[f] = *(const half8*)(BpT + (size_t)(s4 + n_base + f * 16 + l15) * 8);
      half8 af[4];
#pragma unroll
      for (int mf = 0; mf < 4; ++mf) {
        const int px = m_base + mf * 16 + l15 + kj;
        const int bi = cg * 4 + l4;
        af[mf] = *(const half8*)(smA + (ki * 130 + px) * 192 +
                                 (((bi & 24) | ((bi & 7) ^ (px & 7))) << 3));
      }
#pragma unroll
      for (int mf = 0; mf < 4; ++mf)
#pragma unroll
        for (int f = 0; f < 7; ++f)
          acc[mf][f] = __builtin_amdgcn_mfma_f32_16x16x32_f16(af[mf], bf[f], acc[mf][f], 0, 0, 0);
    }
    // tail: ci 192..195 as a l4==0-masked K32 MFMA
    half8 aft[4];
#pragma unroll
    for (int mf = 0; mf < 4; ++mf) {
      const int px = m_base + mf * 16 + l15 + kj;
      const half4 tv = *(const half4*)(smT + (ki * 130 + px) * 4);
      half8 a = {0, 0, 0, 0, 0, 0, 0, 0};
      if (lz) { a[0] = tv[0]; a[1] = tv[1]; a[2] = tv[2]; a[3] = tv[3]; }
      aft[mf] = a;
    }
#pragma unroll
    for (int f = 0; f < 7; ++f) {
      const half4 wv = *(const half4*)(Bt + (size_t)(t * 448 + n_base + f * 16 + l15) * 4);
      half8 bb = {0, 0, 0, 0, 0, 0, 0, 0};
      if (lz) { bb[0] = wv[0]; bb[1] = wv[1]; bb[2] = wv[2]; bb[3] = wv[3]; }
#pragma unroll
      for (int mf = 0; mf < 4; ++mf)
        acc[mf][f] = __builtin_amdgcn_mfma_f32_16x16x32_f16(aft[mf], bb, acc[mf][f], 0, 0, 0);
    }
  }

  // ---- epilogue: activation+flow -> LDS so[128][456] fp16 -> coalesced stores ----
  __syncthreads();
  _Float16* so = smA;
  const int hw0 = h * Ww;
#pragma unroll
  for (int f = 0; f < 7; ++f) {
    const int n = n_base + f * 16 + l15;
    const float bias = (n < COFF) ? b_off[n] : 0.f;
    const bool isOff = (n < 288);
    const float* fl = (n < 144) ? f1 : f2;
    const size_t fladd = (size_t)(b * 2 + ((n & 1) ^ 1)) * HW + hw0;
#pragma unroll
    for (int mf = 0; mf < 4; ++mf) {
#pragma unroll
      for (int rr = 0; rr < 4; ++rr) {
        const int px = m_base + mf * 16 + l4 * 4 + rr;
        const float v = acc[mf][f][rr] + bias;
        float val;
        if (isOff) {
          const float e = __expf(2.f * v);
          val = 10.f * (1.f - 2.f / (e + 1.f)) + fl[fladd + px];
        } else {
          val = 1.f / (1.f + __expf(-v));
        }
        so[px * 456 + n] = (_Float16)val;
      }
    }
  }
  __syncthreads();
  for (int T = tid; T < 4608; T += 512) {
    const int px = T / 36, c = T - px * 36;
    const half8 v = *(const half8*)(so + px * 456 + c * 8);
    *(half8*)(off_pm + ((size_t)b * HW + hw0 + px) * 288 + c * 8) = v;
  }
  for (int T = tid; T < 2304; T += 512) {
    const int px = T / 18, c = T - px * 18;
    const half8 v = *(const half8*)(so + px * 456 + 288 + c * 8);
    *(half8*)(mask_pm + ((size_t)b * HW + hw0 + px) * 144 + c * 8) = v;
  }
}

// ---------------- kernel 2: deform conv, 32 px/block, 8 waves (2 Mh x 4 Kq) ---------------
// grid (4, 128, 2) = 1024 blocks, 512 thr. LDS 74.2KB -> 2 blocks/CU (16 waves/CU).
// Halves per-block overhead and wH panel traffic vs the 16px version.
__global__ __launch_bounds__(512, 2) void k_deform2(
    const _Float16* __restrict__ featT, const _Float16* __restrict__ off_pm,
    const _Float16* __restrict__ mask_pm, const _Float16* __restrict__ wH,
    const float* __restrict__ dcb, float* __restrict__ out) {
  __shared__ __align__(16) char smem[32 * 1160 * 2];   // 74,240 B
  _Float16* sm = (_Float16*)smem;                      // sm[pix 0..31][1160]
  float* red = (float*)smem;                           // red[128 rows][66] (aliased)
  const int w0  = blockIdx.x * 32;
  const int h   = blockIdx.y;
  const int b   = blockIdx.z;
  const int tid = (int)threadIdx.x;
  const int lane = tid & 63, wid = tid >> 6;
  const int l15 = lane & 15, l4 = lane >> 4;

  // phase 0: issue all off/mask loads (9 per thread, 4608 samples)
  half2v offv[9];
  _Float16 mkv[9];
#pragma unroll
  for (int i = 0; i < 9; ++i) {
    const int p   = tid + i * 512;
    const int pix = p / 144;
    const int r   = p - pix * 144;
    const int w   = w0 + pix;
    const int hw  = h * Ww + w;
    offv[i] = *(const half2v*)(off_pm + ((size_t)b * HW + hw) * 288 + 2 * r);
    mkv[i]  = mask_pm[((size_t)b * HW + hw) * 144 + r];
  }
  // phase 1: bilinear gathers (fully unrolled -> feat loads overlap)
#pragma unroll
  for (int i = 0; i < 9; ++i) {
    const int p   = tid + i * 512;
    const int pix = p / 144;
    const int r   = p - pix * 144;
    const int g   = r / 9;
    const int k   = r - g * 9;
    const int w   = w0 + pix;
    const float mk = (float)mkv[i];
    const int ki = (k >= 6) ? 2 : (k >= 3 ? 1 : 0);
    const int kj = k - 3 * ki;
    const float py = (float)(h - 1 + ki) + (float)offv[i][0];
    const float px = (float)(w - 1 + kj) + (float)offv[i][1];
    const float y0f = floorf(py), x0f = floorf(px);
    const int y0 = (int)y0f, x0 = (int)x0f;
    const float ly = py - y0f, lx = px - x0f;
    const float hy = 1.f - ly, hx = 1.f - lx;
    const int y1 = y0 + 1, x1 = x0 + 1;
    const bool vy0 = (unsigned)y0 < (unsigned)Hh, vy1 = (unsigned)y1 < (unsigned)Hh;
    const bool vx0 = (unsigned)x0 < (unsigned)Ww, vx1 = (unsigned)x1 < (unsigned)Ww;
    const float w00 = (vy0 && vx0) ? hy * hx : 0.f;
    const float w01 = (vy0 && vx1) ? hy * lx : 0.f;
    const float w10 = (vy1 && vx0) ? ly * hx : 0.f;
    const float w11 = (vy1 && vx1) ? ly * lx : 0.f;
    const int cy0 = min(max(y0, 0), Hh - 1), cy1 = min(max(y1, 0), Hh - 1);
    const int cx0 = min(max(x0, 0), Ww - 1), cx1 = min(max(x1, 0), Ww - 1);
    const _Float16* gbase = featT + ((size_t)(b * 16 + g) * HW) * 8;
    const half8 s00 = *(const half8*)(gbase + (cy0 * Ww + cx0) * 8);
    const half8 s01 = *(const half8*)(gbase + (cy0 * Ww + cx1) * 8);
    const half8 s10 = *(const half8*)(gbase + (cy1 * Ww + cx0) * 8);
    const half8 s11 = *(const half8*)(gbase + (cy1 * Ww + cx1) * 8);
    half8 v = s00 * splat8(w00) + s01 * splat8(w01) + s10 * splat8(w10) + s11 * splat8(w11);
    v = v * splat8(mk);
    const int swz = (g ^ (k & 7)) << 3;
    *(half8*)(sm + pix * 1160 + k * 128 + swz) = v;
  }
  __syncthreads();

  // phase 2: MFMA. wave = (mh = wid&1 selects 16px, kq = wid>>1 selects K quarter)
  const int mh = wid & 1;
  const int kq = wid >> 1;            // 0..3
  f32x4 acc[4];
#pragma unroll
  for (int nf = 0; nf < 4; ++nf) acc[nf] = (f32x4){0.f, 0.f, 0.f, 0.f};
#pragma unroll
  for (int j = 0; j < 9; ++j) {
    const int s  = kq * 9 + j;        // K32-step 0..35
    const int k  = s >> 2;
    const int cg = s & 3;
    const int gidx = cg * 4 + l4;
    const half8 af = *(const half8*)(sm + (mh * 16 + l15) * 1160 + k * 128 +
                                     ((gidx ^ (k & 7)) << 3));
    const int koff = s * 32 + l4 * 8;
#pragma unroll
    for (int nf = 0; nf < 4; ++nf) {
      const half8 bf = *(const half8*)(wH + (nf * 16 + l15) * 1152 + koff);
      acc[nf] = __builtin_amdgcn_mfma_f32_16x16x32_f16(af, bf, acc[nf], 0, 0, 0);
    }
  }
  __syncthreads();   // done reading sm; alias as red
#pragma unroll
  for (int nf = 0; nf < 4; ++nf)
#pragma unroll
    for (int rr = 0; rr < 4; ++rr)
      red[((mh * 4 + kq) * 16 + l4 * 4 + rr) * 66 + nf * 16 + l15] = acc[nf][rr];
  __syncthreads();

  // reduce 4 K-quarter partials + bias, coalesced store
  for (int T = tid; T < 2048; T += 512) {
    const int px2 = T & 31;
    const int n   = T >> 5;
    const int mhr = px2 >> 4;
    const int pxl = px2 & 15;
    float val = red[((mhr * 4 + 0) * 16 + pxl) * 66 + n] +
                red[((mhr * 4 + 1) * 16 + pxl) * 66 + n] +
                red[((mhr * 4 + 2) * 16 + pxl) * 66 + n] +
                red[((mhr * 4 + 3) * 16 + pxl) * 66 + n];
    out[(size_t)(b * 64 + n) * HW + h * Ww + w0 + px2] = val + dcb[n];
  }
}

extern "C" void kernel_launch(void* const* d_in, const int* in_sizes, int n_in,
                              void* d_out, int out_size, void* d_ws, size_t ws_size,
                              hipStream_t stream) {
  const float* extra = (const float*)d_in[0];
  const float* f1    = (const float*)d_in[1];
  const float* f2    = (const float*)d_in[2];
  const float* fp    = (const float*)d_in[3];
  const float* fn2   = (const float*)d_in[4];
  const float* w_off = (const float*)d_in[5];
  const float* b_off = (const float*)d_in[6];
  const float* dcw   = (const float*)d_in[7];
  const float* dcb   = (const float*)d_in[8];
  float* out = (float*)d_out;

  // ws layout (~40 MB)
  _Float16* off_pm  = (_Float16*)d_ws;                   // 2*HW*288 fp16
  _Float16* mask_pm = off_pm + (size_t)2 * 288 * HW;     // 2*HW*144 fp16
  _Float16* featT   = mask_pm + (size_t)2 * 144 * HW;    // 2*16*HW*8 fp16
  _Float16* BpT     = featT + (size_t)2 * 128 * HW;      // 774144 fp16
  _Float16* Bt      = BpT + 774144;                      // 16128 fp16
  _Float16* wH      = Bt + 16128;                        // 73728 fp16

  hipLaunchKernelGGL(k_prep_all, dim3(815), dim3(256), 0, stream,
                     dcw, w_off, fp, fn2, wH, BpT, Bt, featT);
  hipLaunchKernelGGL(k_offconv_mfma, dim3(128, 2), dim3(512), 0, stream,
                     extra, f1, f2, BpT, Bt, b_off, off_pm, mask_pm);
  hipLaunchKernelGGL(k_deform2, dim3(4, 128, 2), dim3(512), 0, stream,
                     featT, off_pm, mask_pm, wH, dcb, out);
}

// Round 19
// 163.863 us; speedup vs baseline: 1.1362x; 1.0782x over previous
//
#include <hip/hip_runtime.h>
#include <math.h>

#define Hh 128
#define Ww 128
#define HW (128*128)
#define CIN_OFF 196
#define COFF 432

typedef _Float16 half8 __attribute__((ext_vector_type(8)));
typedef _Float16 half4 __attribute__((ext_vector_type(4)));
typedef _Float16 half2v __attribute__((ext_vector_type(2)));
typedef float f32x4 __attribute__((ext_vector_type(4)));

static __device__ __forceinline__ half8 splat8(float v) {
  _Float16 h = (_Float16)v;
  half8 r = {h, h, h, h, h, h, h, h};
  return r;
}

// bijective XCD swizzle (nwg % 8 == 0): consecutive remapped ids share an XCD
static __device__ __forceinline__ int xcd_swz(int bid, int nwg) {
  const int q = nwg >> 3;
  return (bid & 7) * q + (bid >> 3);
}

// ---------------- kernel 0: ALL preprocessing in one launch -------------------------------
__global__ __launch_bounds__(256) void k_prep_all(
    const float* __restrict__ dcw, const float* __restrict__ w_off,
    const float* __restrict__ fp, const float* __restrict__ fn2,
    _Float16* __restrict__ wH, _Float16* __restrict__ BpT, _Float16* __restrict__ Bt,
    _Float16* __restrict__ featT) {
  const int bid = blockIdx.x;
  if (bid < 288) {                     // wH[co][k*128+ci] = dcw[co][ci][k]
    const int idx = bid * 256 + (int)threadIdx.x;
    const int co = idx / 1152;
    const int j  = idx - co * 1152;
    const int k  = j >> 7;
    const int ci = j & 127;
    wH[idx] = (_Float16)dcw[(co * 128 + ci) * 9 + k];
  } else if (bid < 624) {              // BpT[s][l4][n][8]; thread per (n, ci<192)
    const int idx = (bid - 288) * 256 + (int)threadIdx.x;   // 0..86015
    const int n  = idx / 192;          // 0..447
    const int ci = idx - n * 192;      // 0..191
    const int l4 = (ci >> 3) & 3;
    const int c  = ci & 7;
    const int cg = ci >> 5;
    const float* src = w_off + ((size_t)n * CIN_OFF + ci) * 9;
#pragma unroll
    for (int t = 0; t < 9; ++t) {
      const float v = (n < COFF) ? src[t] : 0.f;
      BpT[((size_t)((t * 6 + cg) * 4 + l4) * 448 + n) * 8 + c] = (_Float16)v;
    }
  } else if (bid < 687) {              // Bt[t][n][4] (tail ci 192..195)
    const int j = (bid - 624) * 256 + (int)threadIdx.x;
    if (j < 16128) {
      const int c = j & 3;
      const int n = (j >> 2) % 448;
      const int t = (j >> 2) / 448;
      Bt[j] = (_Float16)((n < COFF) ? w_off[((size_t)n * CIN_OFF + 192 + c) * 9 + t] : 0.f);
    }
  } else {                             // featT[b][g][hw][8c]
    const int t = (bid - 687) * 256 + (int)threadIdx.x;  // 0..32767 = b*HW+hw
    const int b = t >> 14;
    const int hw = t & 16383;
#pragma unroll
    for (int g = 0; g < 16; ++g) {
      const float* src = (g < 8) ? fp : fn2;
      const int ch0 = (g & 7) * 8;
      half8 v;
#pragma unroll
      for (int c = 0; c < 8; ++c)
        v[c] = (_Float16)src[(size_t)(b * 64 + ch0 + c) * HW + hw];
      *(half8*)(featT + (((size_t)(b * 16 + g)) * HW + hw) * 8) = v;
    }
  }
}

// ---------------- kernel 1: offset conv (round-15 core + XCD swizzle + setprio) -----------
// grid 256 (1D; h,b from XCD-swizzled id -> 32 consecutive h per XCD: A rows L2-shared).
// block 512 (8 waves: 2M x 4N, M_wave=64). Full-K LDS, barrier-free K loop.
__global__ __launch_bounds__(512, 2) void k_offconv_mfma(
    const float* __restrict__ extra, const float* __restrict__ f1, const float* __restrict__ f2,
    const _Float16* __restrict__ BpT, const _Float16* __restrict__ Bt,
    const float* __restrict__ b_off,
    _Float16* __restrict__ off_pm, _Float16* __restrict__ mask_pm) {
  __shared__ __align__(16) _Float16 smA[3 * 130 * 192];  // 149,760 B (reused by epilogue)
  __shared__ __align__(16) _Float16 smT[3 * 130 * 4];    //   3,120 B
  const int nb   = xcd_swz((int)blockIdx.x, 256);
  const int h    = nb & 127;
  const int b    = nb >> 7;
  const int tid  = (int)threadIdx.x;
  const int lane = tid & 63;
  const int wid  = tid >> 6;          // 0..7
  const int wm   = wid & 1;
  const int wn   = (wid >> 1) & 3;
  const int m_base = wm * 64;
  const int n_base = wn * 112;
  const int l15 = lane & 15;
  const int l4  = lane >> 4;

  // ---- zero px=0 / px=129 edge columns (grid-stride: 588 tasks) ----
  for (int z = tid; z < 588; z += 512) {
    const int p2 = z % 98;
    const int rr = z / 98;
    const int r  = (rr >= 3) ? (rr - 3) : rr;
    const int px = (rr >= 3) ? 129 : 0;
    if (p2 < 96) {
      const int ci = 2 * p2, biw = ci >> 3;
      const int sw = ((biw & 24) | ((biw & 7) ^ (px & 7))) << 3;
      *(half2v*)(smA + (r * 130 + px) * 192 + sw + (ci & 7)) = (half2v){(_Float16)0.f, (_Float16)0.f};
    } else {
      *(half2v*)(smT + (r * 130 + px) * 4 + 2 * (p2 - 96)) = (half2v){(_Float16)0.f, (_Float16)0.f};
    }
  }

  // ---- main staging: 3 r x 96 ci-pairs x 32 q = 9216 tasks = 18 x 512 ----
#pragma unroll 3
  for (int j = 0; j < 18; ++j) {
    const int J   = tid + 512 * j;
    const int p2a = J & 15;
    const int qa  = (J >> 4) & 3;
    const int R   = J >> 6;                  // 0..143
    const int r   = R / 48;
    const int rem = R - 48 * r;
    const int qh  = rem & 7;
    const int p2h = rem >> 3;                // 0..5
    const int q   = qa + 4 * qh;             // 0..31
    const int p2  = p2a + 16 * p2h;          // 0..95
    const int ci  = 2 * p2;
    const int gh  = h - 1 + r;
    float4 va = {0.f, 0.f, 0.f, 0.f}, vb = va;
    if ((unsigned)gh < (unsigned)Hh) {
      const float* xp = extra + (size_t)(b * 192 + ci) * HW + gh * Ww + 4 * q;
      va = *(const float4*)xp;
      vb = *(const float4*)(xp + HW);
    }
    const float av[4] = {va.x, va.y, va.z, va.w};
    const float bv[4] = {vb.x, vb.y, vb.z, vb.w};
    const int biw = p2 >> 2;
#pragma unroll
    for (int i = 0; i < 4; ++i) {
      const int px = 1 + 4 * q + i;
      const int sw = ((biw & 24) | ((biw & 7) ^ (px & 7))) << 3;
      half2v pk; pk[0] = (_Float16)av[i]; pk[1] = (_Float16)bv[i];
      *(half2v*)(smA + (r * 130 + px) * 192 + sw + (ci & 7)) = pk;
    }
  }
  // ---- tail staging: ci 192..195 (f1, f2) ----
  if (tid < 192) {
    const int q   = tid & 31;
    const int p2t = (tid >> 5) & 1;
    const int r   = tid >> 6;
    const int gh  = h - 1 + r;
    float4 va = {0.f, 0.f, 0.f, 0.f}, vb = va;
    if ((unsigned)gh < (unsigned)Hh) {
      const float* xp = (p2t ? f2 : f1) + (size_t)(b * 2) * HW + gh * Ww + 4 * q;
      va = *(const float4*)xp;
      vb = *(const float4*)(xp + HW);
    }
    const float av[4] = {va.x, va.y, va.z, va.w};
    const float bv[4] = {vb.x, vb.y, vb.z, vb.w};
#pragma unroll
    for (int i = 0; i < 4; ++i) {
      const int px = 1 + 4 * q + i;
      half2v pk; pk[0] = (_Float16)av[i]; pk[1] = (_Float16)bv[i];
      *(half2v*)(smT + (r * 130 + px) * 4 + 2 * p2t) = pk;
    }
  }
  __syncthreads();

  // ---- barrier-free K loop: 9 taps x (6 x K32 + K16-tail), 28 MFMA per step ----
  f32x4 acc[4][7];
#pragma unroll
  for (int i = 0; i < 4; ++i)
#pragma unroll
    for (int j = 0; j < 7; ++j) acc[i][j] = (f32x4){0.f, 0.f, 0.f, 0.f};

  const bool lz = (l4 == 0);
#pragma unroll 3
  for (int t = 0; t < 9; ++t) {
    const int ki = t / 3;
    const int kj = t - 3 * ki;
#pragma unroll
    for (int cg = 0; cg < 6; ++cg) {
      const int s4 = ((t * 6 + cg) * 4 + l4) * 448;
      half8 bf[7];
#pragma unroll
      for (int f = 0; f < 7; ++f)
        bf[f] = *(const half8*)(BpT + (size_t)(s4 + n_base + f * 16 + l15) * 8);
      half8 af[4];
#pragma unroll
      for (int mf = 0; mf < 4; ++mf) {
        const int px = m_base + mf * 16 + l15 + kj;
        const int bi = cg * 4 + l4;
        af[mf] = *(const half8*)(smA + (ki * 130 + px) * 192 +
                                 (((bi & 24) | ((bi & 7) ^ (px & 7))) << 3));
      }
      __builtin_amdgcn_s_setprio(1);
#pragma unroll
      for (int mf = 0; mf < 4; ++mf)
#pragma unroll
        for (int f = 0; f < 7; ++f)
          acc[mf][f] = __builtin_amdgcn_mfma_f32_16x16x32_f16(af[mf], bf[f], acc[mf][f], 0, 0, 0);
      __builtin_amdgcn_s_setprio(0);
    }
    // tail: ci 192..195 as a l4==0-masked K32 MFMA
    half8 aft[4];
#pragma unroll
    for (int mf = 0; mf < 4; ++mf) {
      const int px = m_base + mf * 16 + l15 + kj;
      const half4 tv = *(const half4*)(smT + (ki * 130 + px) * 4);
      half8 a = {0, 0, 0, 0, 0, 0, 0, 0};
      if (lz) { a[0] = tv[0]; a[1] = tv[1]; a[2] = tv[2]; a[3] = tv[3]; }
      aft[mf] = a;
    }
#pragma unroll
    for (int f = 0; f < 7; ++f) {
      const half4 wv = *(const half4*)(Bt + (size_t)(t * 448 + n_base + f * 16 + l15) * 4);
      half8 bb = {0, 0, 0, 0, 0, 0, 0, 0};
      if (lz) { bb[0] = wv[0]; bb[1] = wv[1]; bb[2] = wv[2]; bb[3] = wv[3]; }
      __builtin_amdgcn_s_setprio(1);
#pragma unroll
      for (int mf = 0; mf < 4; ++mf)
        acc[mf][f] = __builtin_amdgcn_mfma_f32_16x16x32_f16(aft[mf], bb, acc[mf][f], 0, 0, 0);
      __builtin_amdgcn_s_setprio(0);
    }
  }

  // ---- epilogue: activation+flow -> LDS so[128][456] fp16 -> coalesced stores ----
  __syncthreads();
  _Float16* so = smA;
  const int hw0 = h * Ww;
#pragma unroll
  for (int f = 0; f < 7; ++f) {
    const int n = n_base + f * 16 + l15;
    const float bias = (n < COFF) ? b_off[n] : 0.f;
    const bool isOff = (n < 288);
    const float* fl = (n < 144) ? f1 : f2;
    const size_t fladd = (size_t)(b * 2 + ((n & 1) ^ 1)) * HW + hw0;
#pragma unroll
    for (int mf = 0; mf < 4; ++mf) {
#pragma unroll
      for (int rr = 0; rr < 4; ++rr) {
        const int px = m_base + mf * 16 + l4 * 4 + rr;
        const float v = acc[mf][f][rr] + bias;
        float val;
        if (isOff) {
          const float e = __expf(2.f * v);
          val = 10.f * (1.f - 2.f / (e + 1.f)) + fl[fladd + px];
        } else {
          val = 1.f / (1.f + __expf(-v));
        }
        so[px * 456 + n] = (_Float16)val;
      }
    }
  }
  __syncthreads();
  for (int T = tid; T < 4608; T += 512) {
    const int px = T / 36, c = T - px * 36;
    const half8 v = *(const half8*)(so + px * 456 + c * 8);
    *(half8*)(off_pm + ((size_t)b * HW + hw0 + px) * 288 + c * 8) = v;
  }
  for (int T = tid; T < 2304; T += 512) {
    const int px = T / 18, c = T - px * 18;
    const half8 v = *(const half8*)(so + px * 456 + 288 + c * 8);
    *(half8*)(mask_pm + ((size_t)b * HW + hw0 + px) * 144 + c * 8) = v;
  }
}

// ---------------- kernel 2: deform conv, 32 px/block + XCD swizzle + setprio --------------
// grid 1024 (1D; XCD-swizzled -> h-adjacent featT gather windows share XCD L2).
__global__ __launch_bounds__(512, 2) void k_deform2(
    const _Float16* __restrict__ featT, const _Float16* __restrict__ off_pm,
    const _Float16* __restrict__ mask_pm, const _Float16* __restrict__ wH,
    const float* __restrict__ dcb, float* __restrict__ out) {
  __shared__ __align__(16) char smem[32 * 1160 * 2];   // 74,240 B
  _Float16* sm = (_Float16*)smem;                      // sm[pix 0..31][1160]
  float* red = (float*)smem;                           // red[128 rows][66] (aliased)
  const int nb  = xcd_swz((int)blockIdx.x, 1024);
  const int w0  = (nb & 3) * 32;
  const int h   = (nb >> 2) & 127;
  const int b   = nb >> 9;
  const int tid = (int)threadIdx.x;
  const int lane = tid & 63, wid = tid >> 6;
  const int l15 = lane & 15, l4 = lane >> 4;

  // phase 0: issue all off/mask loads (9 per thread, 4608 samples)
  half2v offv[9];
  _Float16 mkv[9];
#pragma unroll
  for (int i = 0; i < 9; ++i) {
    const int p   = tid + i * 512;
    const int pix = p / 144;
    const int r   = p - pix * 144;
    const int w   = w0 + pix;
    const int hw  = h * Ww + w;
    offv[i] = *(const half2v*)(off_pm + ((size_t)b * HW + hw) * 288 + 2 * r);
    mkv[i]  = mask_pm[((size_t)b * HW + hw) * 144 + r];
  }
  // phase 1: bilinear gathers (fully unrolled -> feat loads overlap)
#pragma unroll
  for (int i = 0; i < 9; ++i) {
    const int p   = tid + i * 512;
    const int pix = p / 144;
    const int r   = p - pix * 144;
    const int g   = r / 9;
    const int k   = r - g * 9;
    const int w   = w0 + pix;
    const float mk = (float)mkv[i];
    const int ki = (k >= 6) ? 2 : (k >= 3 ? 1 : 0);
    const int kj = k - 3 * ki;
    const float py = (float)(h - 1 + ki) + (float)offv[i][0];
    const float px = (float)(w - 1 + kj) + (float)offv[i][1];
    const float y0f = floorf(py), x0f = floorf(px);
    const int y0 = (int)y0f, x0 = (int)x0f;
    const float ly = py - y0f, lx = px - x0f;
    const float hy = 1.f - ly, hx = 1.f - lx;
    const int y1 = y0 + 1, x1 = x0 + 1;
    const bool vy0 = (unsigned)y0 < (unsigned)Hh, vy1 = (unsigned)y1 < (unsigned)Hh;
    const bool vx0 = (unsigned)x0 < (unsigned)Ww, vx1 = (unsigned)x1 < (unsigned)Ww;
    const float w00 = (vy0 && vx0) ? hy * hx : 0.f;
    const float w01 = (vy0 && vx1) ? hy * lx : 0.f;
    const float w10 = (vy1 && vx0) ? ly * hx : 0.f;
    const float w11 = (vy1 && vx1) ? ly * lx : 0.f;
    const int cy0 = min(max(y0, 0), Hh - 1), cy1 = min(max(y1, 0), Hh - 1);
    const int cx0 = min(max(x0, 0), Ww - 1), cx1 = min(max(x1, 0), Ww - 1);
    const _Float16* gbase = featT + ((size_t)(b * 16 + g) * HW) * 8;
    const half8 s00 = *(const half8*)(gbase + (cy0 * Ww + cx0) * 8);
    const half8 s01 = *(const half8*)(gbase + (cy0 * Ww + cx1) * 8);
    const half8 s10 = *(const half8*)(gbase + (cy1 * Ww + cx0) * 8);
    const half8 s11 = *(const half8*)(gbase + (cy1 * Ww + cx1) * 8);
    half8 v = s00 * splat8(w00) + s01 * splat8(w01) + s10 * splat8(w10) + s11 * splat8(w11);
    v = v * splat8(mk);
    const int swz = (g ^ (k & 7)) << 3;
    *(half8*)(sm + pix * 1160 + k * 128 + swz) = v;
  }
  __syncthreads();

  // phase 2: MFMA. wave = (mh = wid&1 selects 16px, kq = wid>>1 selects K quarter)
  const int mh = wid & 1;
  const int kq = wid >> 1;            // 0..3
  f32x4 acc[4];
#pragma unroll
  for (int nf = 0; nf < 4; ++nf) acc[nf] = (f32x4){0.f, 0.f, 0.f, 0.f};
#pragma unroll
  for (int j = 0; j < 9; ++j) {
    const int s  = kq * 9 + j;        // K32-step 0..35
    const int k  = s >> 2;
    const int cg = s & 3;
    const int gidx = cg * 4 + l4;
    const half8 af = *(const half8*)(sm + (mh * 16 + l15) * 1160 + k * 128 +
                                     ((gidx ^ (k & 7)) << 3));
    const int koff = s * 32 + l4 * 8;
    __builtin_amdgcn_s_setprio(1);
#pragma unroll
    for (int nf = 0; nf < 4; ++nf) {
      const half8 bf = *(const half8*)(wH + (nf * 16 + l15) * 1152 + koff);
      acc[nf] = __builtin_amdgcn_mfma_f32_16x16x32_f16(af, bf, acc[nf], 0, 0, 0);
    }
    __builtin_amdgcn_s_setprio(0);
  }
  __syncthreads();   // done reading sm; alias as red
#pragma unroll
  for (int nf = 0; nf < 4; ++nf)
#pragma unroll
    for (int rr = 0; rr < 4; ++rr)
      red[((mh * 4 + kq) * 16 + l4 * 4 + rr) * 66 + nf * 16 + l15] = acc[nf][rr];
  __syncthreads();

  // reduce 4 K-quarter partials + bias, coalesced store
  for (int T = tid; T < 2048; T += 512) {
    const int px2 = T & 31;
    const int n   = T >> 5;
    const int mhr = px2 >> 4;
    const int pxl = px2 & 15;
    float val = red[((mhr * 4 + 0) * 16 + pxl) * 66 + n] +
                red[((mhr * 4 + 1) * 16 + pxl) * 66 + n] +
                red[((mhr * 4 + 2) * 16 + pxl) * 66 + n] +
                red[((mhr * 4 + 3) * 16 + pxl) * 66 + n];
    out[(size_t)(b * 64 + n) * HW + h * Ww + w0 + px2] = val + dcb[n];
  }
}

extern "C" void kernel_launch(void* const* d_in, const int* in_sizes, int n_in,
                              void* d_out, int out_size, void* d_ws, size_t ws_size,
                              hipStream_t stream) {
  const float* extra = (const float*)d_in[0];
  const float* f1    = (const float*)d_in[1];
  const float* f2    = (const float*)d_in[2];
  const float* fp    = (const float*)d_in[3];
  const float* fn2   = (const float*)d_in[4];
  const float* w_off = (const float*)d_in[5];
  const float* b_off = (const float*)d_in[6];
  const float* dcw   = (const float*)d_in[7];
  const float* dcb   = (const float*)d_in[8];
  float* out = (float*)d_out;

  // ws layout (~40 MB)
  _Float16* off_pm  = (_Float16*)d_ws;                   // 2*HW*288 fp16
  _Float16* mask_pm = off_pm + (size_t)2 * 288 * HW;     // 2*HW*144 fp16
  _Float16* featT   = mask_pm + (size_t)2 * 144 * HW;    // 2*16*HW*8 fp16
  _Float16* BpT     = featT + (size_t)2 * 128 * HW;      // 774144 fp16
  _Float16* Bt      = BpT + 774144;                      // 16128 fp16
  _Float16* wH      = Bt + 16128;                        // 73728 fp16

  hipLaunchKernelGGL(k_prep_all, dim3(815), dim3(256), 0, stream,
                     dcw, w_off, fp, fn2, wH, BpT, Bt, featT);
  hipLaunchKernelGGL(k_offconv_mfma, dim3(256), dim3(512), 0, stream,
                     extra, f1, f2, BpT, Bt, b_off, off_pm, mask_pm);
  hipLaunchKernelGGL(k_deform2, dim3(1024), dim3(512), 0, stream,
                     featT, off_pm, mask_pm, wH, dcb, out);
}